// Round 8
// baseline (413.289 us; speedup 1.0000x reference)
//
#include <hip/hip_runtime.h>

// PETP_Quadratic R11: 2 M-tiles/wave (arithmetic-intensity doubling) +
// coalesced LDS-transposed epilogue.
//   R10 post-mortem: barrier removal neutral -> binder is B-traffic/latency
//   per MFMA (160 MFMA-cyc vs 3 dependent loads/chunk), plus write-amp
//   (122 MB) from scattered 4B stores w/ write-allocate fetch.
//   R11: wave owns 64 pos = 2 accumulator tiles -> 10 MFMA per B-chunk,
//   B stream per wave halves, latency slack doubles. kh-major chunk order
//   (kh*32+u) keeps only half the A-slices live -> fits ~250 unified regs
//   (2 waves/SIMD, __launch_bounds__(192,2)). Block = 3 waves = 192 pos =
//   32 batches, feat 49,152 B, grid 512 = 2 blocks/CU. B rotation carries
//   across variants (refill wraps into next variant's chunks 0,1).
//   Epilogue: scatter acc into wave-private 16 KB LDS slice, read back as
//   float4 -> 1 KB full-line global stores (no partial lines).

typedef _Float16 half8   __attribute__((ext_vector_type(8)));
typedef _Float16 half4_t __attribute__((ext_vector_type(4)));
typedef float    f32x16  __attribute__((ext_vector_type(16)));
typedef float    float4_t __attribute__((ext_vector_type(4)));

#define NORM 0.022097086912079608f   /* 1/(32*sqrt(2)) */
#define INV_SQRT3 0.5773502691896258f

// ---------------- prep: fragment-swizzled f16 weights ----------------
// Chunk ci = kh*32 + u (64 per variant, kh-major); frag index =
// (t*64 + ci)*3 + fr, fr in {0=A,1=G,2=V}; frag = 512 half (1KB):
// element lane*8+j with lane n = lane&31, kq = lane>>5,
// k-channel v = kh*16 + kq*8 + j.
//   A: NORM*W0[u][v][n]   G: NORM*INV_SQRT3*W1[u][v][n]
//   V: NORM*(W2[u][v][n] + W3[v][u][n])
__global__ void prep_kernel(const float* __restrict__ Wa, const float* __restrict__ Wb,
                            const float* __restrict__ Wc, const float* __restrict__ Wd,
                            _Float16* __restrict__ Ball) {
    int idx = blockIdx.x * 256 + threadIdx.x;   // 0..49151
    if (idx >= 49152) return;
    int lane = idx & 63;
    int frag = idx >> 6;          // 0..767, wave-uniform
    int fr = frag % 3;
    int q  = frag / 3;            // t*64 + kh*32 + u
    int u  = q & 31;
    int kh = (q >> 5) & 1;
    int t  = q >> 6;
    int n = lane & 31, kq = lane >> 5;
    const float* Ws[4] = {Wa, Wb, Wc, Wd};
    const float* W = Ws[t];
    half8 out;
#pragma unroll
    for (int j = 0; j < 8; ++j) {
        int v = kh * 16 + kq * 8 + j;
        float val;
        if (fr == 0)      val = NORM * W[u * 1024 + v * 32 + n];
        else if (fr == 1) val = NORM * INV_SQRT3 * W[32768 + u * 1024 + v * 32 + n];
        else              val = NORM * (W[65536 + u * 1024 + v * 32 + n] +
                                        W[98304 + v * 1024 + u * 32 + n]);
        out[j] = (_Float16)val;
    }
    *(half8*)(Ball + (size_t)frag * 512 + lane * 8) = out;
}

// ---------------- main kernel ----------------
// WG = 192 thr (3 waves) owns 32 batches = 192 positions; wave owns 64
// (2 M-tiles). feat[pos][ch] pos-major, 16B-chunk XOR swizzle:
// half index = pos*128 + (((ch>>3) ^ (pos&7))<<3) + (ch&7).
__launch_bounds__(192, 2)
__global__ void petp_main(const float* __restrict__ x,
                          const _Float16* __restrict__ Ball,
                          float* __restrict__ y) {
    __shared__ _Float16 feat[192 * 128];   // 49,152 B

    const int tid  = threadIdx.x;
    const int wave = tid >> 6;
    const int lane = tid & 63;
    const int mw = lane & 31;   // A row within tile AND C/D col n
    const int q8 = lane >> 5;

    f32x16 accS[2];
    f32x16 accV[2][3];
#pragma unroll
    for (int tl = 0; tl < 2; ++tl)
#pragma unroll
        for (int r = 0; r < 16; ++r) {
            accS[tl][r] = 0.f;
            accV[tl][0][r] = 0.f; accV[tl][1][r] = 0.f; accV[tl][2][r] = 0.f;
        }

    const int wg = blockIdx.x;
    const float* xg = x + (size_t)wg * (192 * 128);

    const _Float16* f0 = feat + (wave * 64 + mw) * 128;        // tile0 row
    const _Float16* f1 = f0 + 32 * 128;                        // tile1 row
    const int px = mw & 7;   // pos&7 (tile offsets are 32 -> same for both)

    // depth-2 B rotation, carried across variants
    half8 pA[2], pG[2], pV[2];
    {
        const _Float16* B0 = Ball + lane * 8;
        pA[0] = *(const half8*)(B0);
        pG[0] = *(const half8*)(B0 + 512);
        pV[0] = *(const half8*)(B0 + 1024);
        pA[1] = *(const half8*)(B0 + 1536);
        pG[1] = *(const half8*)(B0 + 2048);
        pV[1] = *(const half8*)(B0 + 2560);
    }

#pragma unroll 1
    for (int t = 0; t < 4; ++t) {
        __syncthreads();   // prior variant's feat readers done

        // ---- build variant-t features (float4 loads), 32 batches ----
#pragma unroll
        for (int it = 0; it < 6; ++it) {
            int item = it * 192 + tid;        // 32 batches x 32 ch-groups
            if (item < 1024) {
                int b  = item >> 5;
                int cg = item & 31;
                const float* bp = xg + b * 768 + cg * 4;
                float4_t v00 = *(const float4_t*)(bp);
                float4_t v01 = *(const float4_t*)(bp + 128);
                float4_t v02 = *(const float4_t*)(bp + 256);
                float4_t v10 = *(const float4_t*)(bp + 384);
                float4_t v11 = *(const float4_t*)(bp + 512);
                float4_t v12 = *(const float4_t*)(bp + 640);
                float4_t rs0 = v00 + v01 + v02, rs1 = v10 + v11 + v12;
                float4_t tot = rs0 + rs1;
                float4_t xv[6] = {v00, v01, v02, v10, v11, v12};
                float4_t rs[2] = {rs0, rs1};
                float4_t cs[3] = {v00 + v10, v01 + v11, v02 + v12};
#pragma unroll
                for (int p6 = 0; p6 < 6; ++p6) {
                    int i = p6 / 3, j = p6 % 3;
                    float4_t f;
                    if      (t == 0) f = xv[p6];
                    else if (t == 1) f = (rs[i] - xv[p6]) * 0.5f;
                    else if (t == 2) f = cs[j] - xv[p6];
                    else             f = (tot - rs[i] - cs[j] + xv[p6]) * 0.5f;
                    int pos = b * 6 + p6;
                    int base = pos * 128;
                    int pxs = pos & 7;
                    if (cg < 8) {   // s-rows: 4 contiguous halves, one b64 store
                        int row0 = cg * 4;
                        int addr = base + ((((row0 >> 3) ^ pxs) << 3) | (row0 & 7));
                        half4_t h4 = {(_Float16)f[0], (_Float16)f[1],
                                      (_Float16)f[2], (_Float16)f[3]};
                        *(half4_t*)(feat + addr) = h4;
                    } else {        // v-rows: scattered
#pragma unroll
                        for (int c4 = 0; c4 < 4; ++c4) {
                            int cc = cg * 4 + c4 - 32;
                            int row = 32 + (cc % 3) * 32 + cc / 3;
                            feat[base + ((((row >> 3) ^ pxs) << 3) | (row & 7))] =
                                (_Float16)f[c4];
                        }
                    }
                }
            }
        }
        __syncthreads();   // feat published

        const _Float16* Bl = Ball + t * 98304 + lane * 8;

#pragma unroll
        for (int kh = 0; kh < 2; ++kh) {
            // A-side k-slices for this kh half (only half live at a time)
            half8 slS[2];
            half8 slV[2][3];
#pragma unroll
            for (int tl = 0; tl < 2; ++tl) {
                const _Float16* fp = tl ? f1 : f0;
                slS[tl] = *(const half8*)(fp + (((kh * 2 + q8) ^ px) << 3));
#pragma unroll
                for (int i = 0; i < 3; ++i)
                    slV[tl][i] = *(const half8*)(fp + (((4 + i * 4 + kh * 2 + q8) ^ px) << 3));
            }

#pragma unroll 1
            for (int cb = 0; cb < 4; ++cb) {
                // broadcast chunks for u = cb*8 .. cb*8+7, both tiles
                half8 bcS[2], bcG0[2], bcG1[2], bcG2[2];
#pragma unroll
                for (int tl = 0; tl < 2; ++tl) {
                    const _Float16* fp = tl ? f1 : f0;
                    bcS[tl]  = *(const half8*)(fp + ((cb ^ px) << 3));
                    bcG0[tl] = *(const half8*)(fp + (((4 + cb) ^ px) << 3));
                    bcG1[tl] = *(const half8*)(fp + (((8 + cb) ^ px) << 3));
                    bcG2[tl] = *(const half8*)(fp + (((12 + cb) ^ px) << 3));
                }

#pragma unroll
                for (int k = 0; k < 8; ++k) {
                    const int ci = kh * 32 + cb * 8 + k;   // chunk index (cb runtime)
                    const int sl = k & 1;                   // compile-time slot

                    __builtin_amdgcn_s_setprio(1);
                    half8 af;
#pragma unroll
                    for (int tl = 0; tl < 2; ++tl) {
                        _Float16 su = bcS[tl][k];
                        _Float16 g0 = bcG0[tl][k], g1 = bcG1[tl][k], g2 = bcG2[tl][k];
                        // ys: s.s^T
                        af = slS[tl] * su;
                        accS[tl] = __builtin_amdgcn_mfma_f32_32x32x16_f16(af, pA[sl], accS[tl], 0, 0, 0);
                        // ys: Gram(v)
                        af = slV[tl][0] * g0 + slV[tl][1] * g1 + slV[tl][2] * g2;
                        accS[tl] = __builtin_amdgcn_mfma_f32_32x32x16_f16(af, pG[sl], accS[tl], 0, 0, 0);
                        // yv: s[u] v[v,kc]
#pragma unroll
                        for (int kc = 0; kc < 3; ++kc) {
                            half8 afv = slV[tl][kc] * su;
                            accV[tl][kc] = __builtin_amdgcn_mfma_f32_32x32x16_f16(afv, pV[sl], accV[tl][kc], 0, 0, 0);
                        }
                    }
                    __builtin_amdgcn_s_setprio(0);

                    // refill slot with chunk ci+2. For ci=62,63 this wraps into
                    // the NEXT variant's chunks 0,1 (prologue folded in);
                    // skip only at the very end (t==3).
                    if (t < 3 || ci < 62) {
                        const _Float16* Bn = Bl + (size_t)(ci + 2) * 1536;
                        pA[sl] = *(const half8*)(Bn);
                        pG[sl] = *(const half8*)(Bn + 512);
                        pV[sl] = *(const half8*)(Bn + 1024);
                    }
                }
            }
        }
    }

    // ---- epilogue: per-wave LDS transpose -> full-line coalesced stores ----
    // wave-private slice = its own feat region (16 KB = 4096 f32 = 32 pos).
    // No cross-wave sync needed: each wave only overwrites rows it alone read.
    asm volatile("s_waitcnt lgkmcnt(0)" ::: "memory");
    __builtin_amdgcn_sched_barrier(0);
    float* slice = (float*)feat + wave * 4096;
    float* yg = y + (size_t)wg * (192 * 128) + wave * 64 * 128;
#pragma unroll
    for (int tl = 0; tl < 2; ++tl) {
        // scatter this tile's accs: C/D layout col=mw, row=(r&3)+8*(r>>2)+4*q8
#pragma unroll
        for (int r = 0; r < 16; ++r) {
            int posl = (r & 3) + 8 * (r >> 2) + 4 * q8;   // 0..31
            float* bp = slice + posl * 128;
            bp[mw] = accS[tl][r];
            bp[32 + 3 * mw + 0] = accV[tl][0][r];
            bp[32 + 3 * mw + 1] = accV[tl][1][r];
            bp[32 + 3 * mw + 2] = accV[tl][2][r];
        }
        asm volatile("s_waitcnt lgkmcnt(0)" ::: "memory");
        __builtin_amdgcn_sched_barrier(0);
        // coalesced read-back + full-line stores (1 KB per instruction)
#pragma unroll
        for (int i = 0; i < 16; ++i) {
            int item = i * 64 + lane;
            int posl = item >> 5;
            int grp  = item & 31;
            float4_t v = *(const float4_t*)(slice + posl * 128 + grp * 4);
            *(float4_t*)(yg + (tl * 32 + posl) * 128 + grp * 4) = v;
        }
        asm volatile("s_waitcnt lgkmcnt(0)" ::: "memory");   // reads done before
        __builtin_amdgcn_sched_barrier(0);                   // next tile's scatter
    }
}

extern "C" void kernel_launch(void* const* d_in, const int* in_sizes, int n_in,
                              void* d_out, int out_size, void* d_ws, size_t ws_size,
                              hipStream_t stream) {
    const float* x  = (const float*)d_in[0];
    const float* Wa = (const float*)d_in[1];
    const float* Wb = (const float*)d_in[2];
    const float* Wc = (const float*)d_in[3];
    const float* Wd = (const float*)d_in[4];
    float* y = (float*)d_out;

    _Float16* Ball = (_Float16*)d_ws;          // 393216 half = 768 KB

    int nbatch = in_sizes[0] / 768;            // 16384
    int nwg = nbatch / 32;                     // 512 = 2 blocks/CU exactly

    prep_kernel<<<192, 256, 0, stream>>>(Wa, Wb, Wc, Wd, Ball);
    petp_main<<<nwg, 192, 0, stream>>>(x, Ball, y);
}